// Round 5
// baseline (960.157 us; speedup 1.0000x reference)
//
#include <hip/hip_runtime.h>
#include <stdint.h>

#define TTOK 1024
#define DMODEL 1024
#define NEXP 16
#define TOPK 4
#define INTER 512
#define NSHI 1024
#define RSCALE 2.5f

typedef __bf16 bf16;
typedef __bf16 bf16x8 __attribute__((ext_vector_type(8)));
typedef __bf16 bf16x4 __attribute__((ext_vector_type(4)));
typedef float f32x4 __attribute__((ext_vector_type(4)));

// LDS oct-plane strides (+16B pad to spread write banks)
#define APLANE 2064   // 128 rows * 16B + 16
#define BPLANE 1040   // 64 rows * 16B + 16
#define BPLANE32 528  // 32 rows * 16B + 16

// ---------------- scores (+ fused x->bf16): logits = x @ gw^T, fp32 exact ----------------
__global__ __launch_bounds__(256)
void scores_kernel(const float* __restrict__ x, const float* __restrict__ gw,
                   float* __restrict__ scores, bf16* __restrict__ xbf) {
  __shared__ float gws[16 * 1024];
  const int tid = threadIdx.x;
  const float4* gw4 = (const float4*)gw;
#pragma unroll
  for (int i0 = 0; i0 < 4096; i0 += 256) {
    const int i = i0 + tid;
    const int e = i >> 8;
    const int dq = (i & 255) << 2;
    const int dd = (dq + 4 * e) & 1023;
    ((float4*)gws)[(e << 8) + (dd >> 2)] = gw4[i];
  }
  {
    const long xb = (long)blockIdx.x * 1024;
#pragma unroll
    for (int p = 0; p < 4; ++p) {
      const long j = xb + p * 256 + tid;
      const float4 v = ((const float4*)x)[j];
      bf16x4 o;
      o.x = (bf16)v.x; o.y = (bf16)v.y; o.z = (bf16)v.z; o.w = (bf16)v.w;
      ((bf16x4*)xbf)[j] = o;
    }
  }
  __syncthreads();
  const int kq = tid >> 6;
  const int lane = tid & 63;
  const int tl = lane >> 4;
  const int e = lane & 15;
  const long token = (long)blockIdx.x * 4 + tl;
  float acc = 0.f;
  const int dbase = kq * 256;
#pragma unroll 8
  for (int i = 0; i < 256; i += 4) {
    const int d = dbase + i;
    const float4 xv = *(const float4*)&x[token * DMODEL + d];
    const float4 wv = *(const float4*)&gws[(e << 10) + ((d + 4 * e) & 1023)];
    acc += xv.x * wv.x + xv.y * wv.y + xv.z * wv.z + xv.w * wv.w;
  }
  __syncthreads();
  gws[kq * 64 + lane] = acc;
  __syncthreads();
  if (kq == 0) {
    const float s = gws[lane] + gws[64 + lane] + gws[128 + lane] + gws[192 + lane];
    scores[token * 16 + e] = s;
  }
}

// ---------------- top-k: one thread per token ----------------
__global__ __launch_bounds__(256)
void topk_kernel(const float* __restrict__ scores, const float* __restrict__ gb,
                 int* __restrict__ tokIdx, float* __restrict__ tokW,
                 int* __restrict__ counts) {
  __shared__ int h[NEXP];
  const int tid = threadIdx.x;
  if (tid < NEXP) h[tid] = 0;
  __syncthreads();
  const int t = blockIdx.x * 256 + tid;
  float sc[NEXP], s[NEXP];
#pragma unroll
  for (int e = 0; e < NEXP; ++e) {
    const float l = scores[t * NEXP + e];
    sc[e] = 1.f / (1.f + expf(-l));
    s[e] = sc[e] + gb[e];
  }
  float gsc[4];
#pragma unroll
  for (int g = 0; g < 4; ++g) {
    const float a = s[4 * g], b = s[4 * g + 1], c = s[4 * g + 2], d = s[4 * g + 3];
    gsc[g] = fmaxf(fmaxf(fmaxf(a + b, a + c), fmaxf(a + d, b + c)),
                   fmaxf(b + d, c + d));
  }
  int g0 = 0;
  for (int g = 1; g < 4; ++g) if (gsc[g] > gsc[g0]) g0 = g;
  int g1 = (g0 == 0) ? 1 : 0;
  for (int g = 0; g < 4; ++g) if (g != g0 && gsc[g] > gsc[g1]) g1 = g;
  float m[NEXP];
#pragma unroll
  for (int e = 0; e < NEXP; ++e) {
    const int g = e >> 2;
    m[e] = (g == g0 || g == g1) ? s[e] : -1.f;
  }
  int idx[TOPK]; float wv[TOPK]; float wsum = 0.f;
  for (int k = 0; k < TOPK; ++k) {
    int am = 0; float best = m[0];
    for (int e2 = 1; e2 < NEXP; ++e2)
      if (m[e2] > best) { best = m[e2]; am = e2; }
    idx[k] = am; wv[k] = sc[am]; wsum += sc[am]; m[am] = -2.f;
  }
  const float scl = RSCALE / wsum;
  for (int k = 0; k < TOPK; ++k) {
    tokIdx[t * TOPK + k] = idx[k];
    tokW[t * TOPK + k] = wv[k] * scl;
    atomicAdd(&h[idx[k]], 1);
  }
  __syncthreads();
  if (tid < NEXP) atomicAdd(&counts[tid], h[tid]);
}

// ---------------- plan: offsets + flattened tile list ----------------
__global__ void plan_kernel(const int* __restrict__ counts, int* __restrict__ offs,
                            int* __restrict__ cursors, int* __restrict__ tileE,
                            int* __restrict__ tileR, int* __restrict__ tileCnt) {
  if (threadIdx.x == 0) {
    int acc = 0;
    for (int e = 0; e < NEXP; ++e) { offs[e] = acc; cursors[e] = acc; acc += counts[e]; }
    offs[NEXP] = acc;
    int tc = 0;
    for (int e = 0; e < NEXP; ++e)
      for (int r = offs[e]; r < offs[e + 1]; r += 128) { tileE[tc] = e; tileR[tc] = r; ++tc; }
    for (int r = 0; r < TTOK; r += 128) { tileE[tc] = NEXP; tileR[tc] = r; ++tc; }
    tileCnt[0] = tc;  // <= 48 + 8 = 56
  }
}

// ---------------- fill: slot lists + token->slot map ----------------
__global__ __launch_bounds__(256)
void fill_kernel(const int* __restrict__ tokIdx, int* __restrict__ cursors,
                 int* __restrict__ slotTok, int* __restrict__ tokSlot) {
  __shared__ int h[NEXP], base[NEXP];
  const int tid = threadIdx.x;
  if (tid < NEXP) h[tid] = 0;
  __syncthreads();
  const int t = blockIdx.x * 256 + tid;
  int myE[TOPK], myR[TOPK];
#pragma unroll
  for (int k = 0; k < TOPK; ++k) {
    myE[k] = tokIdx[t * TOPK + k];
    myR[k] = atomicAdd(&h[myE[k]], 1);
  }
  __syncthreads();
  if (tid < NEXP) base[tid] = atomicAdd(&cursors[tid], h[tid]);
  __syncthreads();
#pragma unroll
  for (int k = 0; k < TOPK; ++k) {
    const int slot = base[myE[k]] + myR[k];
    slotTok[slot] = t;
    tokSlot[t * TOPK + k] = slot;
  }
}

// ---------------- gate+up grouped GEMM (128M x 32N, BK=64), 2-deep prefetch ----------------
__global__ __launch_bounds__(256, 3)
void gateup_gemm(const bf16* __restrict__ xbf, const int* __restrict__ slotTok,
                 const int* __restrict__ offs, const int* __restrict__ tileE,
                 const int* __restrict__ tileR, const int* __restrict__ tileCnt,
                 const float* __restrict__ Wg, const float* __restrict__ Wu,
                 const float* __restrict__ Sg, const float* __restrict__ Su,
                 bf16* __restrict__ interR, bf16* __restrict__ interS) {
  const int y = blockIdx.y;
  if (y >= tileCnt[0]) return;
  const int e = tileE[y];
  const bool shd = (e == NEXP);
  const int n0 = blockIdx.x * 32;
  if (!shd && n0 >= INTER) return;
  const int rowStart = tileR[y];
  const int rowEnd = shd ? rowStart + 128 : offs[e + 1];
  const float* wgp = shd ? Sg : Wg + (long)e * INTER * DMODEL;
  const float* wup = shd ? Su : Wu + (long)e * INTER * DMODEL;

  __shared__ __attribute__((aligned(16))) char As[8 * APLANE];
  __shared__ __attribute__((aligned(16))) char Bg[8 * BPLANE32];
  __shared__ __attribute__((aligned(16))) char Bu[8 * BPLANE32];
  __shared__ int tokS[128];

  const int tid = threadIdx.x;
  if (tid < 128) {
    const int r = rowStart + tid;
    tokS[tid] = shd ? r : slotTok[r < rowEnd ? r : rowStart];
  }
  __syncthreads();

  // A staging: round p: row = p*32 + (tid>>3), oct = tid&7 (8 rows x 128B / instr)
  const int arw = tid >> 3;
  const int aoct = tid & 7;
  const bf16* aSrc[4];
#pragma unroll
  for (int p = 0; p < 4; ++p)
    aSrc[p] = xbf + (long)tokS[p * 32 + arw] * DMODEL + aoct * 8;

  // B staging: 128 threads/matrix; round p: row = p*8 + (u>>4), f4 = u&15 (256B rows)
  const int bu_ = tid >> 7;
  const int u = tid & 127;
  const int brw = u >> 4;
  const int bf4 = u & 15;
  const int boct = bf4 >> 1;
  const int bhalf = bf4 & 1;
  const float* bSrc = (bu_ ? wup : wgp) + (long)n0 * DMODEL + bf4 * 4;
  char* bDst = bu_ ? Bu : Bg;

  const int lane = tid & 63;
  const int wv = tid >> 6;
  const int q = lane >> 4;
  const int l15 = lane & 15;
  const int wm = (wv >> 1) * 64;
  const int wn = (wv & 1) * 16;

  const f32x4 fz = {0.f, 0.f, 0.f, 0.f};
  f32x4 accG[4], accU[4];
#pragma unroll
  for (int i = 0; i < 4; ++i) { accG[i] = fz; accU[i] = fz; }

  bf16x8 av[2][4];
  float4 bv[2][4];
#pragma unroll
  for (int s = 0; s < 2; ++s) {
#pragma unroll
    for (int p = 0; p < 4; ++p) av[s][p] = *(const bf16x8*)(aSrc[p] + s * 64);
#pragma unroll
    for (int p = 0; p < 4; ++p)
      bv[s][p] = *(const float4*)(bSrc + (long)(p * 8 + brw) * DMODEL + s * 64);
  }

  int s = 0;
  for (int k0 = 0; k0 < DMODEL; k0 += 64, s ^= 1) {
    __syncthreads();  // prior fragment reads complete
#pragma unroll
    for (int p = 0; p < 4; ++p)
      *(bf16x8*)(As + aoct * APLANE + (p * 32 + arw) * 16) = av[s][p];
#pragma unroll
    for (int p = 0; p < 4; ++p) {
      bf16x4 w;
      w.x = (bf16)bv[s][p].x; w.y = (bf16)bv[s][p].y;
      w.z = (bf16)bv[s][p].z; w.w = (bf16)bv[s][p].w;
      *(bf16x4*)(bDst + boct * BPLANE32 + (p * 8 + brw) * 16 + bhalf * 8) = w;
    }
    const int kn = k0 + 128;  // refill the stage just consumed (used 2 iters later)
    if (kn < DMODEL) {
#pragma unroll
      for (int p = 0; p < 4; ++p) av[s][p] = *(const bf16x8*)(aSrc[p] + kn);
#pragma unroll
      for (int p = 0; p < 4; ++p)
        bv[s][p] = *(const float4*)(bSrc + (long)(p * 8 + brw) * DMODEL + kn);
    }
    __syncthreads();
#pragma unroll
    for (int kb = 0; kb < 2; ++kb) {
      const int pl = 4 * kb + q;
      bf16x8 aF[4];
#pragma unroll
      for (int mi = 0; mi < 4; ++mi)
        aF[mi] = *(const bf16x8*)(As + pl * APLANE + (wm + 16 * mi + l15) * 16);
      const bf16x8 gF = *(const bf16x8*)(Bg + pl * BPLANE32 + (wn + l15) * 16);
      const bf16x8 uF = *(const bf16x8*)(Bu + pl * BPLANE32 + (wn + l15) * 16);
#pragma unroll
      for (int mi = 0; mi < 4; ++mi) {
        accG[mi] = __builtin_amdgcn_mfma_f32_16x16x32_bf16(aF[mi], gF, accG[mi], 0, 0, 0);
        accU[mi] = __builtin_amdgcn_mfma_f32_16x16x32_bf16(aF[mi], uF, accU[mi], 0, 0, 0);
      }
    }
  }

  bf16* outI = shd ? interS : interR;
  const int ldI = shd ? NSHI : INTER;
  const int col = n0 + wn + l15;
#pragma unroll
  for (int mi = 0; mi < 4; ++mi)
#pragma unroll
    for (int r = 0; r < 4; ++r) {
      const int rowLoc = wm + 16 * mi + q * 4 + r;
      const int row = rowStart + rowLoc;
      if (row < rowEnd) {
        const float gg = accG[mi][r];
        const float uu = accU[mi][r];
        const float sv = gg / (1.f + __expf(-gg)) * uu;
        outI[(long)row * ldI + col] = (bf16)sv;
      }
    }
}

// ---------------- down grouped GEMM (128M x 64N, BK=64), 2-deep prefetch ----------------
__global__ __launch_bounds__(256, 3)
void down_gemm(const bf16* __restrict__ interR, const bf16* __restrict__ interS,
               const int* __restrict__ offs, const int* __restrict__ tileE,
               const int* __restrict__ tileR, const int* __restrict__ tileCnt,
               const float* __restrict__ Wd, const float* __restrict__ Sd,
               float* __restrict__ dsR, float* __restrict__ dsS) {
  const int y = blockIdx.y;
  if (y >= tileCnt[0]) return;
  const int e = tileE[y];
  const bool shd = (e == NEXP);
  const int n0 = blockIdx.x * 64;
  const int rowStart = tileR[y];
  const int rowEnd = shd ? rowStart + 128 : offs[e + 1];
  const int Kd = shd ? NSHI : INTER;
  const bf16* A = shd ? interS : interR;
  const float* wd = shd ? Sd : Wd + (long)e * DMODEL * INTER;

  __shared__ __attribute__((aligned(16))) char As[8 * APLANE];
  __shared__ __attribute__((aligned(16))) char Bs[8 * BPLANE];

  const int tid = threadIdx.x;
  const int arw = tid >> 3;
  const int aoct = tid & 7;
  const bf16* aSrc[4];
#pragma unroll
  for (int p = 0; p < 4; ++p)
    aSrc[p] = A + (long)(rowStart + p * 32 + arw) * Kd + aoct * 8;

  const int brw = tid >> 4;
  const int bf4 = tid & 15;
  const int boct = bf4 >> 1;
  const int bhalf = bf4 & 1;
  const float* bSrc = wd + (long)n0 * Kd + bf4 * 4;

  const int lane = tid & 63;
  const int wv = tid >> 6;
  const int q = lane >> 4;
  const int l15 = lane & 15;
  const int wm = (wv >> 1) * 64;
  const int wn = (wv & 1) * 32;

  const f32x4 fz = {0.f, 0.f, 0.f, 0.f};
  f32x4 acc[4][2];
#pragma unroll
  for (int i = 0; i < 4; ++i)
#pragma unroll
    for (int j = 0; j < 2; ++j) acc[i][j] = fz;

  bf16x8 av[2][4];
  float4 bv[2][4];
#pragma unroll
  for (int s = 0; s < 2; ++s) {
#pragma unroll
    for (int p = 0; p < 4; ++p) av[s][p] = *(const bf16x8*)(aSrc[p] + s * 64);
#pragma unroll
    for (int p = 0; p < 4; ++p)
      bv[s][p] = *(const float4*)(bSrc + (long)(p * 16 + brw) * Kd + s * 64);
  }

  int s = 0;
  for (int k0 = 0; k0 < Kd; k0 += 64, s ^= 1) {
    __syncthreads();
#pragma unroll
    for (int p = 0; p < 4; ++p)
      *(bf16x8*)(As + aoct * APLANE + (p * 32 + arw) * 16) = av[s][p];
#pragma unroll
    for (int p = 0; p < 4; ++p) {
      bf16x4 w;
      w.x = (bf16)bv[s][p].x; w.y = (bf16)bv[s][p].y;
      w.z = (bf16)bv[s][p].z; w.w = (bf16)bv[s][p].w;
      *(bf16x4*)(Bs + boct * BPLANE + (p * 16 + brw) * 16 + bhalf * 8) = w;
    }
    const int kn = k0 + 128;
    if (kn < Kd) {
#pragma unroll
      for (int p = 0; p < 4; ++p) av[s][p] = *(const bf16x8*)(aSrc[p] + kn);
#pragma unroll
      for (int p = 0; p < 4; ++p)
        bv[s][p] = *(const float4*)(bSrc + (long)(p * 16 + brw) * Kd + kn);
    }
    __syncthreads();
#pragma unroll
    for (int kb = 0; kb < 2; ++kb) {
      const int pl = 4 * kb + q;
      bf16x8 aF[4];
#pragma unroll
      for (int mi = 0; mi < 4; ++mi)
        aF[mi] = *(const bf16x8*)(As + pl * APLANE + (wm + 16 * mi + l15) * 16);
#pragma unroll
      for (int ni = 0; ni < 2; ++ni) {
        const bf16x8 bF = *(const bf16x8*)(Bs + pl * BPLANE + (wn + 16 * ni + l15) * 16);
#pragma unroll
        for (int mi = 0; mi < 4; ++mi)
          acc[mi][ni] = __builtin_amdgcn_mfma_f32_16x16x32_bf16(aF[mi], bF, acc[mi][ni], 0, 0, 0);
      }
    }
  }

  float* dst = shd ? dsS : dsR;
#pragma unroll
  for (int mi = 0; mi < 4; ++mi)
#pragma unroll
    for (int r = 0; r < 4; ++r) {
      const int rowLoc = wm + 16 * mi + q * 4 + r;
      const int row = rowStart + rowLoc;
      if (row < rowEnd) {
#pragma unroll
        for (int ni = 0; ni < 2; ++ni)
          dst[(long)row * DMODEL + (n0 + wn + 16 * ni + l15)] = acc[mi][ni][r];
      }
    }
}

// ---------------- combine: out[t] = shared[t] + sum_k w * routed[slot_k] ----------------
__global__ __launch_bounds__(256)
void combine_kernel(const float* __restrict__ dsR, const float* __restrict__ dsS,
                    const int* __restrict__ tokSlot, const float* __restrict__ tokW,
                    float* __restrict__ out) {
  const int t = blockIdx.x;
  const int j = threadIdx.x;
  float4 v = ((const float4*)(dsS + (long)t * DMODEL))[j];
#pragma unroll
  for (int k = 0; k < TOPK; ++k) {
    const int s = tokSlot[t * TOPK + k];
    const float w = tokW[t * TOPK + k];
    const float4 r = ((const float4*)(dsR + (long)s * DMODEL))[j];
    v.x += w * r.x; v.y += w * r.y; v.z += w * r.z; v.w += w * r.w;
  }
  ((float4*)(out + (long)t * DMODEL))[j] = v;
}

extern "C" void kernel_launch(void* const* d_in, const int* in_sizes, int n_in,
                              void* d_out, int out_size, void* d_ws, size_t ws_size,
                              hipStream_t stream) {
  const float* x  = (const float*)d_in[0];
  const float* gw = (const float*)d_in[2];
  const float* gb = (const float*)d_in[3];
  const float* gp = (const float*)d_in[4];
  const float* up = (const float*)d_in[5];
  const float* dp = (const float*)d_in[6];
  const float* sg = (const float*)d_in[7];
  const float* su = (const float*)d_in[8];
  const float* sd = (const float*)d_in[9];
  float* out = (float*)d_out;

  char* base = (char*)d_ws;
  size_t off = 0;
  auto alloc = [&](size_t bytes) -> char* {
    off = (off + 255) & ~(size_t)255;
    char* p = base + off;
    off += bytes;
    return p;
  };
  bf16* xbf = (bf16*)alloc((size_t)TTOK * DMODEL * 2);
  bf16* interR = (bf16*)alloc((size_t)(TTOK * TOPK + 128) * INTER * 2);
  bf16* interS = (bf16*)alloc((size_t)TTOK * NSHI * 2);
  float* dsR = (float*)alloc((size_t)TTOK * TOPK * DMODEL * 4);
  float* dsS = (float*)alloc((size_t)TTOK * DMODEL * 4);
  float* scores = (float*)alloc((size_t)TTOK * NEXP * 4);
  int* tokIdx = (int*)alloc(TTOK * TOPK * 4);
  float* tokW = (float*)alloc(TTOK * TOPK * 4);
  int* slotTok = (int*)alloc(TTOK * TOPK * 4);
  int* tokSlot = (int*)alloc(TTOK * TOPK * 4);
  int* counts = (int*)alloc(NEXP * 4);
  int* offs = (int*)alloc((NEXP + 1) * 4);
  int* cursors = (int*)alloc(NEXP * 4);
  int* tileE = (int*)alloc(72 * 4);
  int* tileR = (int*)alloc(72 * 4);
  int* tileCnt = (int*)alloc(4);

  hipMemsetAsync(counts, 0, NEXP * 4, stream);

  scores_kernel<<<TTOK / 4, 256, 0, stream>>>(x, gw, scores, xbf);
  topk_kernel<<<TTOK / 256, 256, 0, stream>>>(scores, gb, tokIdx, tokW, counts);
  plan_kernel<<<1, 64, 0, stream>>>(counts, offs, cursors, tileE, tileR, tileCnt);
  fill_kernel<<<TTOK / 256, 256, 0, stream>>>(tokIdx, cursors, slotTok, tokSlot);

  // gateup: N-tile 32 -> up to 32 x-tiles (shared), 16 (routed); ~1008 active blocks
  gateup_gemm<<<dim3(32, 56, 1), 256, 0, stream>>>(
      xbf, slotTok, offs, tileE, tileR, tileCnt, gp, up, sg, su, interR, interS);
  // down: N-tile 64 -> 16 x-tiles; ~880 active blocks
  down_gemm<<<dim3(16, 56, 1), 256, 0, stream>>>(
      interR, interS, offs, tileE, tileR, tileCnt, dp, sd, dsR, dsS);
  combine_kernel<<<TTOK, 256, 0, stream>>>(dsR, dsS, tokSlot, tokW, out);
}

// Round 6
// 234.899 us; speedup vs baseline: 4.0875x; 4.0875x over previous
//
#include <hip/hip_runtime.h>
#include <stdint.h>

#define TTOK 1024
#define DMODEL 1024
#define NEXP 16
#define TOPK 4
#define INTER 512
#define NSHI 1024
#define RSCALE 2.5f

typedef __bf16 bf16;
typedef __bf16 bf16x8 __attribute__((ext_vector_type(8)));
typedef __bf16 bf16x4 __attribute__((ext_vector_type(4)));
typedef float f32x4 __attribute__((ext_vector_type(4)));

// LDS oct-plane strides (+16B pad to spread write banks)
#define APLANE 2064   // 128 rows * 16B + 16
#define BPLANE 1040   // 64 rows * 16B + 16
#define BPLANE32 528  // 32 rows * 16B + 16

// ---------------- scores (+ fused x->bf16): logits = x @ gw^T, fp32 exact ----------------
__global__ __launch_bounds__(256)
void scores_kernel(const float* __restrict__ x, const float* __restrict__ gw,
                   float* __restrict__ scores, bf16* __restrict__ xbf) {
  __shared__ float gws[16 * 1024];
  const int tid = threadIdx.x;
  const float4* gw4 = (const float4*)gw;
#pragma unroll
  for (int i0 = 0; i0 < 4096; i0 += 256) {
    const int i = i0 + tid;
    const int e = i >> 8;
    const int dq = (i & 255) << 2;
    const int dd = (dq + 4 * e) & 1023;
    ((float4*)gws)[(e << 8) + (dd >> 2)] = gw4[i];
  }
  {
    const long xb = (long)blockIdx.x * 1024;
#pragma unroll
    for (int p = 0; p < 4; ++p) {
      const long j = xb + p * 256 + tid;
      const float4 v = ((const float4*)x)[j];
      bf16x4 o;
      o.x = (bf16)v.x; o.y = (bf16)v.y; o.z = (bf16)v.z; o.w = (bf16)v.w;
      ((bf16x4*)xbf)[j] = o;
    }
  }
  __syncthreads();
  const int kq = tid >> 6;
  const int lane = tid & 63;
  const int tl = lane >> 4;
  const int e = lane & 15;
  const long token = (long)blockIdx.x * 4 + tl;
  float acc = 0.f;
  const int dbase = kq * 256;
#pragma unroll 8
  for (int i = 0; i < 256; i += 4) {
    const int d = dbase + i;
    const float4 xv = *(const float4*)&x[token * DMODEL + d];
    const float4 wv = *(const float4*)&gws[(e << 10) + ((d + 4 * e) & 1023)];
    acc += xv.x * wv.x + xv.y * wv.y + xv.z * wv.z + xv.w * wv.w;
  }
  __syncthreads();
  gws[kq * 64 + lane] = acc;
  __syncthreads();
  if (kq == 0) {
    const float s = gws[lane] + gws[64 + lane] + gws[128 + lane] + gws[192 + lane];
    scores[token * 16 + e] = s;
  }
}

// ---------------- top-k: one thread per token ----------------
__global__ __launch_bounds__(256)
void topk_kernel(const float* __restrict__ scores, const float* __restrict__ gb,
                 int* __restrict__ tokIdx, float* __restrict__ tokW,
                 int* __restrict__ counts) {
  __shared__ int h[NEXP];
  const int tid = threadIdx.x;
  if (tid < NEXP) h[tid] = 0;
  __syncthreads();
  const int t = blockIdx.x * 256 + tid;
  float sc[NEXP], s[NEXP];
#pragma unroll
  for (int e = 0; e < NEXP; ++e) {
    const float l = scores[t * NEXP + e];
    sc[e] = 1.f / (1.f + expf(-l));
    s[e] = sc[e] + gb[e];
  }
  float gsc[4];
#pragma unroll
  for (int g = 0; g < 4; ++g) {
    const float a = s[4 * g], b = s[4 * g + 1], c = s[4 * g + 2], d = s[4 * g + 3];
    gsc[g] = fmaxf(fmaxf(fmaxf(a + b, a + c), fmaxf(a + d, b + c)),
                   fmaxf(b + d, c + d));
  }
  int g0 = 0;
  for (int g = 1; g < 4; ++g) if (gsc[g] > gsc[g0]) g0 = g;
  int g1 = (g0 == 0) ? 1 : 0;
  for (int g = 0; g < 4; ++g) if (g != g0 && gsc[g] > gsc[g1]) g1 = g;
  float m[NEXP];
#pragma unroll
  for (int e = 0; e < NEXP; ++e) {
    const int g = e >> 2;
    m[e] = (g == g0 || g == g1) ? s[e] : -1.f;
  }
  int idx[TOPK]; float wv[TOPK]; float wsum = 0.f;
  for (int k = 0; k < TOPK; ++k) {
    int am = 0; float best = m[0];
    for (int e2 = 1; e2 < NEXP; ++e2)
      if (m[e2] > best) { best = m[e2]; am = e2; }
    idx[k] = am; wv[k] = sc[am]; wsum += sc[am]; m[am] = -2.f;
  }
  const float scl = RSCALE / wsum;
  for (int k = 0; k < TOPK; ++k) {
    tokIdx[t * TOPK + k] = idx[k];
    tokW[t * TOPK + k] = wv[k] * scl;
    atomicAdd(&h[idx[k]], 1);
  }
  __syncthreads();
  if (tid < NEXP) atomicAdd(&counts[tid], h[tid]);
}

// ---------------- plan: offsets + flattened tile list ----------------
__global__ void plan_kernel(const int* __restrict__ counts, int* __restrict__ offs,
                            int* __restrict__ cursors, int* __restrict__ tileE,
                            int* __restrict__ tileR, int* __restrict__ tileCnt) {
  if (threadIdx.x == 0) {
    int acc = 0;
    for (int e = 0; e < NEXP; ++e) { offs[e] = acc; cursors[e] = acc; acc += counts[e]; }
    offs[NEXP] = acc;
    int tc = 0;
    for (int e = 0; e < NEXP; ++e)
      for (int r = offs[e]; r < offs[e + 1]; r += 128) { tileE[tc] = e; tileR[tc] = r; ++tc; }
    for (int r = 0; r < TTOK; r += 128) { tileE[tc] = NEXP; tileR[tc] = r; ++tc; }
    tileCnt[0] = tc;  // <= 48 + 8 = 56
  }
}

// ---------------- fill: slot lists + token->slot map ----------------
__global__ __launch_bounds__(256)
void fill_kernel(const int* __restrict__ tokIdx, int* __restrict__ cursors,
                 int* __restrict__ slotTok, int* __restrict__ tokSlot) {
  __shared__ int h[NEXP], base[NEXP];
  const int tid = threadIdx.x;
  if (tid < NEXP) h[tid] = 0;
  __syncthreads();
  const int t = blockIdx.x * 256 + tid;
  int myE[TOPK], myR[TOPK];
#pragma unroll
  for (int k = 0; k < TOPK; ++k) {
    myE[k] = tokIdx[t * TOPK + k];
    myR[k] = atomicAdd(&h[myE[k]], 1);
  }
  __syncthreads();
  if (tid < NEXP) base[tid] = atomicAdd(&cursors[tid], h[tid]);
  __syncthreads();
#pragma unroll
  for (int k = 0; k < TOPK; ++k) {
    const int slot = base[myE[k]] + myR[k];
    slotTok[slot] = t;
    tokSlot[t * TOPK + k] = slot;
  }
}

// ---------------- gate+up grouped GEMM (128M x 32N, BK=64), static 2-stage pipeline ----------------
__global__ __launch_bounds__(256, 3)
void gateup_gemm(const bf16* __restrict__ xbf, const int* __restrict__ slotTok,
                 const int* __restrict__ offs, const int* __restrict__ tileE,
                 const int* __restrict__ tileR, const int* __restrict__ tileCnt,
                 const float* __restrict__ Wg, const float* __restrict__ Wu,
                 const float* __restrict__ Sg, const float* __restrict__ Su,
                 bf16* __restrict__ interR, bf16* __restrict__ interS) {
  const int y = blockIdx.y;
  if (y >= tileCnt[0]) return;
  const int e = tileE[y];
  const bool shd = (e == NEXP);
  const int n0 = blockIdx.x * 32;
  if (!shd && n0 >= INTER) return;
  const int rowStart = tileR[y];
  const int rowEnd = shd ? rowStart + 128 : offs[e + 1];
  const float* wgp = shd ? Sg : Wg + (long)e * INTER * DMODEL;
  const float* wup = shd ? Su : Wu + (long)e * INTER * DMODEL;

  __shared__ __attribute__((aligned(16))) char As[8 * APLANE];
  __shared__ __attribute__((aligned(16))) char Bg[8 * BPLANE32];
  __shared__ __attribute__((aligned(16))) char Bu[8 * BPLANE32];
  __shared__ int tokS[128];

  const int tid = threadIdx.x;
  if (tid < 128) {
    const int r = rowStart + tid;
    tokS[tid] = shd ? r : slotTok[r < rowEnd ? r : rowStart];
  }
  __syncthreads();

  // A staging: round p: row = p*32 + (tid>>3), oct = tid&7 (8 rows x 128B / instr)
  const int arw = tid >> 3;
  const int aoct = tid & 7;
  const bf16* aSrc[4];
#pragma unroll
  for (int p = 0; p < 4; ++p)
    aSrc[p] = xbf + (long)tokS[p * 32 + arw] * DMODEL + aoct * 8;

  // B staging: 128 threads/matrix; round p: row = p*8 + (u>>4), f4 = u&15 (256B rows)
  const int bu_ = tid >> 7;
  const int u = tid & 127;
  const int brw = u >> 4;
  const int bf4 = u & 15;
  const int boct = bf4 >> 1;
  const int bhalf = bf4 & 1;
  const float* bSrc = (bu_ ? wup : wgp) + (long)n0 * DMODEL + bf4 * 4;
  char* bDst = bu_ ? Bu : Bg;

  const int lane = tid & 63;
  const int wv = tid >> 6;
  const int q = lane >> 4;
  const int l15 = lane & 15;
  const int wm = (wv >> 1) * 64;
  const int wn = (wv & 1) * 16;

  const f32x4 fz = {0.f, 0.f, 0.f, 0.f};
  f32x4 accG[4], accU[4];
#pragma unroll
  for (int i = 0; i < 4; ++i) { accG[i] = fz; accU[i] = fz; }

  // STATIC 2-stage register pipeline (named sets -> no dynamic indexing -> no scratch)
  bf16x8 av0[4], av1[4];
  float4 bv0[4], bv1[4];
#pragma unroll
  for (int p = 0; p < 4; ++p) {
    av0[p] = *(const bf16x8*)(aSrc[p]);
    av1[p] = *(const bf16x8*)(aSrc[p] + 64);
    bv0[p] = *(const float4*)(bSrc + (long)(p * 8 + brw) * DMODEL);
    bv1[p] = *(const float4*)(bSrc + (long)(p * 8 + brw) * DMODEL + 64);
  }

#define GU_STAGE(AV, BV, KNEXT)                                              \
  {                                                                          \
    __syncthreads();                                                         \
    _Pragma("unroll") for (int p = 0; p < 4; ++p)                            \
        *(bf16x8*)(As + aoct * APLANE + (p * 32 + arw) * 16) = AV[p];        \
    _Pragma("unroll") for (int p = 0; p < 4; ++p) {                          \
      bf16x4 w;                                                              \
      w.x = (bf16)BV[p].x; w.y = (bf16)BV[p].y;                              \
      w.z = (bf16)BV[p].z; w.w = (bf16)BV[p].w;                              \
      *(bf16x4*)(bDst + boct * BPLANE32 + (p * 8 + brw) * 16 + bhalf * 8) = w; \
    }                                                                        \
    if ((KNEXT) < DMODEL) {                                                  \
      _Pragma("unroll") for (int p = 0; p < 4; ++p) {                        \
        AV[p] = *(const bf16x8*)(aSrc[p] + (KNEXT));                         \
        BV[p] = *(const float4*)(bSrc + (long)(p * 8 + brw) * DMODEL + (KNEXT)); \
      }                                                                      \
    }                                                                        \
    __syncthreads();                                                         \
    _Pragma("unroll") for (int kb = 0; kb < 2; ++kb) {                       \
      const int pl = 4 * kb + q;                                             \
      bf16x8 aF[4];                                                          \
      _Pragma("unroll") for (int mi = 0; mi < 4; ++mi)                       \
          aF[mi] = *(const bf16x8*)(As + pl * APLANE + (wm + 16 * mi + l15) * 16); \
      const bf16x8 gF = *(const bf16x8*)(Bg + pl * BPLANE32 + (wn + l15) * 16); \
      const bf16x8 uF = *(const bf16x8*)(Bu + pl * BPLANE32 + (wn + l15) * 16); \
      _Pragma("unroll") for (int mi = 0; mi < 4; ++mi) {                     \
        accG[mi] = __builtin_amdgcn_mfma_f32_16x16x32_bf16(aF[mi], gF, accG[mi], 0, 0, 0); \
        accU[mi] = __builtin_amdgcn_mfma_f32_16x16x32_bf16(aF[mi], uF, accU[mi], 0, 0, 0); \
      }                                                                      \
    }                                                                        \
  }

  for (int k0 = 0; k0 < DMODEL; k0 += 128) {
    GU_STAGE(av0, bv0, k0 + 128);
    GU_STAGE(av1, bv1, k0 + 192);
  }
#undef GU_STAGE

  bf16* outI = shd ? interS : interR;
  const int ldI = shd ? NSHI : INTER;
  const int col = n0 + wn + l15;
#pragma unroll
  for (int mi = 0; mi < 4; ++mi)
#pragma unroll
    for (int r = 0; r < 4; ++r) {
      const int rowLoc = wm + 16 * mi + q * 4 + r;
      const int row = rowStart + rowLoc;
      if (row < rowEnd) {
        const float gg = accG[mi][r];
        const float uu = accU[mi][r];
        const float sv = gg / (1.f + __expf(-gg)) * uu;
        outI[(long)row * ldI + col] = (bf16)sv;
      }
    }
}

// ---------------- down grouped GEMM (128M x 64N, BK=64), static 2-stage pipeline ----------------
__global__ __launch_bounds__(256, 3)
void down_gemm(const bf16* __restrict__ interR, const bf16* __restrict__ interS,
               const int* __restrict__ offs, const int* __restrict__ tileE,
               const int* __restrict__ tileR, const int* __restrict__ tileCnt,
               const float* __restrict__ Wd, const float* __restrict__ Sd,
               float* __restrict__ dsR, float* __restrict__ dsS) {
  const int y = blockIdx.y;
  if (y >= tileCnt[0]) return;
  const int e = tileE[y];
  const bool shd = (e == NEXP);
  const int n0 = blockIdx.x * 64;
  const int rowStart = tileR[y];
  const int rowEnd = shd ? rowStart + 128 : offs[e + 1];
  const int Kd = shd ? NSHI : INTER;   // runtime, but stage indices below are static
  const bf16* A = shd ? interS : interR;
  const float* wd = shd ? Sd : Wd + (long)e * DMODEL * INTER;

  __shared__ __attribute__((aligned(16))) char As[8 * APLANE];
  __shared__ __attribute__((aligned(16))) char Bs[8 * BPLANE];

  const int tid = threadIdx.x;
  const int arw = tid >> 3;
  const int aoct = tid & 7;
  const bf16* aSrc[4];
#pragma unroll
  for (int p = 0; p < 4; ++p)
    aSrc[p] = A + (long)(rowStart + p * 32 + arw) * Kd + aoct * 8;

  const int brw = tid >> 4;
  const int bf4 = tid & 15;
  const int boct = bf4 >> 1;
  const int bhalf = bf4 & 1;
  const float* bSrc = wd + (long)n0 * Kd + bf4 * 4;

  const int lane = tid & 63;
  const int wv = tid >> 6;
  const int q = lane >> 4;
  const int l15 = lane & 15;
  const int wm = (wv >> 1) * 64;
  const int wn = (wv & 1) * 32;

  const f32x4 fz = {0.f, 0.f, 0.f, 0.f};
  f32x4 acc[4][2];
#pragma unroll
  for (int i = 0; i < 4; ++i)
#pragma unroll
    for (int j = 0; j < 2; ++j) acc[i][j] = fz;

  bf16x8 av0[4], av1[4];
  float4 bv0[4], bv1[4];
#pragma unroll
  for (int p = 0; p < 4; ++p) {
    av0[p] = *(const bf16x8*)(aSrc[p]);
    av1[p] = *(const bf16x8*)(aSrc[p] + 64);
    bv0[p] = *(const float4*)(bSrc + (long)(p * 16 + brw) * Kd);
    bv1[p] = *(const float4*)(bSrc + (long)(p * 16 + brw) * Kd + 64);
  }

#define DN_STAGE(AV, BV, KNEXT)                                              \
  {                                                                          \
    __syncthreads();                                                         \
    _Pragma("unroll") for (int p = 0; p < 4; ++p)                            \
        *(bf16x8*)(As + aoct * APLANE + (p * 32 + arw) * 16) = AV[p];        \
    _Pragma("unroll") for (int p = 0; p < 4; ++p) {                          \
      bf16x4 w;                                                              \
      w.x = (bf16)BV[p].x; w.y = (bf16)BV[p].y;                              \
      w.z = (bf16)BV[p].z; w.w = (bf16)BV[p].w;                              \
      *(bf16x4*)(Bs + boct * BPLANE + (p * 16 + brw) * 16 + bhalf * 8) = w;  \
    }                                                                        \
    if ((KNEXT) < Kd) {                                                      \
      _Pragma("unroll") for (int p = 0; p < 4; ++p) {                        \
        AV[p] = *(const bf16x8*)(aSrc[p] + (KNEXT));                         \
        BV[p] = *(const float4*)(bSrc + (long)(p * 16 + brw) * Kd + (KNEXT)); \
      }                                                                      \
    }                                                                        \
    __syncthreads();                                                         \
    _Pragma("unroll") for (int kb = 0; kb < 2; ++kb) {                       \
      const int pl = 4 * kb + q;                                             \
      bf16x8 aF[4];                                                          \
      _Pragma("unroll") for (int mi = 0; mi < 4; ++mi)                       \
          aF[mi] = *(const bf16x8*)(As + pl * APLANE + (wm + 16 * mi + l15) * 16); \
      _Pragma("unroll") for (int ni = 0; ni < 2; ++ni) {                     \
        const bf16x8 bF = *(const bf16x8*)(Bs + pl * BPLANE + (wn + 16 * ni + l15) * 16); \
        _Pragma("unroll") for (int mi = 0; mi < 4; ++mi)                     \
            acc[mi][ni] = __builtin_amdgcn_mfma_f32_16x16x32_bf16(aF[mi], bF, acc[mi][ni], 0, 0, 0); \
      }                                                                      \
    }                                                                        \
  }

  for (int k0 = 0; k0 < Kd; k0 += 128) {
    DN_STAGE(av0, bv0, k0 + 128);
    DN_STAGE(av1, bv1, k0 + 192);
  }
#undef DN_STAGE

  float* dst = shd ? dsS : dsR;
#pragma unroll
  for (int mi = 0; mi < 4; ++mi)
#pragma unroll
    for (int r = 0; r < 4; ++r) {
      const int rowLoc = wm + 16 * mi + q * 4 + r;
      const int row = rowStart + rowLoc;
      if (row < rowEnd) {
#pragma unroll
        for (int ni = 0; ni < 2; ++ni)
          dst[(long)row * DMODEL + (n0 + wn + 16 * ni + l15)] = acc[mi][ni][r];
      }
    }
}

// ---------------- combine: out[t] = shared[t] + sum_k w * routed[slot_k] ----------------
__global__ __launch_bounds__(256)
void combine_kernel(const float* __restrict__ dsR, const float* __restrict__ dsS,
                    const int* __restrict__ tokSlot, const float* __restrict__ tokW,
                    float* __restrict__ out) {
  const int t = blockIdx.x;
  const int j = threadIdx.x;
  float4 v = ((const float4*)(dsS + (long)t * DMODEL))[j];
#pragma unroll
  for (int k = 0; k < TOPK; ++k) {
    const int s = tokSlot[t * TOPK + k];
    const float w = tokW[t * TOPK + k];
    const float4 r = ((const float4*)(dsR + (long)s * DMODEL))[j];
    v.x += w * r.x; v.y += w * r.y; v.z += w * r.z; v.w += w * r.w;
  }
  ((float4*)(out + (long)t * DMODEL))[j] = v;
}

extern "C" void kernel_launch(void* const* d_in, const int* in_sizes, int n_in,
                              void* d_out, int out_size, void* d_ws, size_t ws_size,
                              hipStream_t stream) {
  const float* x  = (const float*)d_in[0];
  const float* gw = (const float*)d_in[2];
  const float* gb = (const float*)d_in[3];
  const float* gp = (const float*)d_in[4];
  const float* up = (const float*)d_in[5];
  const float* dp = (const float*)d_in[6];
  const float* sg = (const float*)d_in[7];
  const float* su = (const float*)d_in[8];
  const float* sd = (const float*)d_in[9];
  float* out = (float*)d_out;

  char* base = (char*)d_ws;
  size_t off = 0;
  auto alloc = [&](size_t bytes) -> char* {
    off = (off + 255) & ~(size_t)255;
    char* p = base + off;
    off += bytes;
    return p;
  };
  bf16* xbf = (bf16*)alloc((size_t)TTOK * DMODEL * 2);
  bf16* interR = (bf16*)alloc((size_t)(TTOK * TOPK + 128) * INTER * 2);
  bf16* interS = (bf16*)alloc((size_t)TTOK * NSHI * 2);
  float* dsR = (float*)alloc((size_t)TTOK * TOPK * DMODEL * 4);
  float* dsS = (float*)alloc((size_t)TTOK * DMODEL * 4);
  float* scores = (float*)alloc((size_t)TTOK * NEXP * 4);
  int* tokIdx = (int*)alloc(TTOK * TOPK * 4);
  float* tokW = (float*)alloc(TTOK * TOPK * 4);
  int* slotTok = (int*)alloc(TTOK * TOPK * 4);
  int* tokSlot = (int*)alloc(TTOK * TOPK * 4);
  int* counts = (int*)alloc(NEXP * 4);
  int* offs = (int*)alloc((NEXP + 1) * 4);
  int* cursors = (int*)alloc(NEXP * 4);
  int* tileE = (int*)alloc(72 * 4);
  int* tileR = (int*)alloc(72 * 4);
  int* tileCnt = (int*)alloc(4);

  hipMemsetAsync(counts, 0, NEXP * 4, stream);

  scores_kernel<<<TTOK / 4, 256, 0, stream>>>(x, gw, scores, xbf);
  topk_kernel<<<TTOK / 256, 256, 0, stream>>>(scores, gb, tokIdx, tokW, counts);
  plan_kernel<<<1, 64, 0, stream>>>(counts, offs, cursors, tileE, tileR, tileCnt);
  fill_kernel<<<TTOK / 256, 256, 0, stream>>>(tokIdx, cursors, slotTok, tokSlot);

  // gateup: N-tile 32 -> 32 x-tiles (shared), 16 (routed); ~1008 active blocks
  gateup_gemm<<<dim3(32, 56, 1), 256, 0, stream>>>(
      xbf, slotTok, offs, tileE, tileR, tileCnt, gp, up, sg, su, interR, interS);
  // down: N-tile 64 -> 16 x-tiles; ~880 active blocks
  down_gemm<<<dim3(16, 56, 1), 256, 0, stream>>>(
      interR, interS, offs, tileE, tileR, tileCnt, dp, sd, dsR, dsS);
  combine_kernel<<<TTOK, 256, 0, stream>>>(dsR, dsS, tokSlot, tokW, out);
}